// Round 7
// baseline (150.397 us; speedup 1.0000x reference)
//
#include <hip/hip_runtime.h>
#include <hip/hip_bf16.h>

#define BATCH 4
#define SEQ   2048
#define EMB   1024
#define HD    64
#define BT    (BATCH * SEQ)

// logits scale 1/sqrt(64) folded with log2(e) so softmax can use exp2 directly
#define QSCALE 0.18033688011112042f

typedef __attribute__((ext_vector_type(8))) short bf16x8;
typedef __attribute__((ext_vector_type(4))) float f32x4;

__device__ __forceinline__ ushort f2bf(float f) {   // RTN fp32 -> bf16 bits
    unsigned u = __float_as_uint(f);
    return (ushort)((u + 0x7FFFu + ((u >> 16) & 1u)) >> 16);
}

// ---------------- prep: W (fp32) -> Wb bf16 [192][1024]; biases -> fp32[192]
__global__ __launch_bounds__(256) void prep(
    const float* __restrict__ Wq, const float* __restrict__ bq,
    const float* __restrict__ Wk, const float* __restrict__ bk,
    const float* __restrict__ Wv, const float* __restrict__ bv,
    ushort* __restrict__ Wb, float* __restrict__ bb)
{
    const int r = (int)blockIdx.x;                    // 0..191
    const float* W = (r < 64) ? Wq : ((r < 128) ? Wk : Wv);
    const float* src = W + (size_t)(r & 63) * EMB;
    ushort* dst = Wb + (size_t)r * EMB;
    for (int e = (int)threadIdx.x; e < EMB; e += 256) dst[e] = f2bf(src[e]);
    if (blockIdx.x == 0 && threadIdx.x < 192) {
        const int i = (int)threadIdx.x;
        const float* B = (i < 64) ? bq : ((i < 128) ? bk : bv);
        bb[i] = B[i & 63];
    }
}

// ---------------- QKV pass 1: block = (16-row tile, EMB slice of 128) -------
// 4096 one-wave blocks; no LDS, no barriers. fp32 partials to ws.
// A frag: m = lane&15, k = quad*8+j ; B frag: n = lane&15 (Wb row sub*16+col)
// C/D   : col = lane&15, row = quad*4 + reg        (layout HW-verified R2/R3)
__global__ __launch_bounds__(64) void qkv_part(
    const float* __restrict__ x, const ushort* __restrict__ Wb,
    float* __restrict__ part)                         // [512][8][12][16][16]
{
    const int blk  = (int)blockIdx.x;
    const int tile = blk >> 3, sl = blk & 7;
    const int t0   = tile * 16;
    const int lane = (int)threadIdx.x;
    const int col  = lane & 15, quad = lane >> 4;

    const float*  ap = x  + (size_t)(t0 + col) * EMB + sl * 128 + quad * 8;
    const ushort* bp = Wb + (size_t)col * EMB + sl * 128 + quad * 8;

    f32x4 acc[12];
    #pragma unroll
    for (int s = 0; s < 12; ++s) acc[s] = (f32x4){0.f, 0.f, 0.f, 0.f};

    #pragma unroll 2
    for (int k0 = 0; k0 < 128; k0 += 32) {
        const float4 a0 = *(const float4*)(ap + k0);
        const float4 a1 = *(const float4*)(ap + k0 + 4);
        bf16x8 a;
        a[0] = (short)f2bf(a0.x); a[1] = (short)f2bf(a0.y);
        a[2] = (short)f2bf(a0.z); a[3] = (short)f2bf(a0.w);
        a[4] = (short)f2bf(a1.x); a[5] = (short)f2bf(a1.y);
        a[6] = (short)f2bf(a1.z); a[7] = (short)f2bf(a1.w);
        #pragma unroll
        for (int sub = 0; sub < 12; ++sub) {
            const bf16x8 bf = *(const bf16x8*)(bp + (size_t)sub * 16 * EMB + k0);
            acc[sub] = __builtin_amdgcn_mfma_f32_16x16x32_bf16(a, bf, acc[sub], 0, 0, 0);
        }
    }

    float* pp = part + (size_t)blk * 12 * 256;
    #pragma unroll
    for (int sub = 0; sub < 12; ++sub)
        #pragma unroll
        for (int i = 0; i < 4; ++i)
            pp[sub * 256 + (quad * 4 + i) * 16 + col] = acc[sub][i];
}

// ---------------- QKV pass 2: sum 8 slices + bias, pack q/k/v^T bf16 --------
__global__ __launch_bounds__(256) void qkv_pack(
    const float* __restrict__ part, const float* __restrict__ bb,
    ushort* __restrict__ qb, ushort* __restrict__ kbuf, ushort* __restrict__ vtb)
{
    const int tile = (int)blockIdx.x;
    const int t0   = tile * 16;
    const int tid  = (int)threadIdx.x;
    const int row  = tid >> 4, c = tid & 15;
    const float* pp = part + (size_t)tile * 8 * 12 * 256;
    const int b = t0 >> 11;
    const int sloc = (t0 & (SEQ - 1)) + row;

    #pragma unroll
    for (int sub = 0; sub < 12; ++sub) {
        float s = bb[sub * 16 + c];
        #pragma unroll
        for (int sl = 0; sl < 8; ++sl)
            s += pp[(sl * 12 + sub) * 256 + row * 16 + c];
        if (sub < 4)
            qb[(size_t)(t0 + row) * HD + sub * 16 + c] = f2bf(s * QSCALE);
        else if (sub < 8)
            kbuf[(size_t)(t0 + row) * HD + (sub - 4) * 16 + c] = f2bf(s);
        else
            vtb[((size_t)(b * 64 + (sub - 8) * 16 + c)) * SEQ + sloc] = f2bf(s);
    }
}

// ---------------- attention pass 1: block = (b, 16 q-rows, key-split j/8) ---
// 4096 one-wave blocks, <=4 K-tile iters each; unnormalized (m,l,O) partials.
__global__ __launch_bounds__(64) void attn_part(
    const ushort* __restrict__ qb, const ushort* __restrict__ kbuf,
    const ushort* __restrict__ vtb,
    float* __restrict__ pm, float* __restrict__ pl, float* __restrict__ pO)
{
    const int idx  = (int)blockIdx.x;
    const int j    = idx & 7;
    const int rest = idx >> 3;
    const int b    = rest & 3;
    const int tile = 127 - (rest >> 2);               // longest tiles dispatch first
    const int t0   = tile * 16;
    const int nt   = (tile >> 2) + 1;                 // K-tiles of 64 covering s<=t0+15
    const int lane = (int)threadIdx.x;
    const int col  = lane & 15, quad = lane >> 4;

    const ushort* q  = qb   + ((size_t)b * SEQ + t0) * HD;
    const ushort* kb = kbuf + (size_t)b * SEQ * HD;
    const ushort* vb = vtb  + (size_t)b * HD * SEQ;

    const bf16x8 aq0 = *(const bf16x8*)(q + col * HD + quad * 8);
    const bf16x8 aq1 = *(const bf16x8*)(q + col * HD + 32 + quad * 8);

    float m_r[4], l_r[4];
    f32x4 o[4];
    #pragma unroll
    for (int i = 0; i < 4; ++i) { m_r[i] = -1e30f; l_r[i] = 0.f; o[i] = (f32x4){0.f,0.f,0.f,0.f}; }

    __shared__ ushort pt[16][72];                     // P transpose tile (one wave)

    for (int it = j; it < nt; it += 8) {
        const int s0 = it * 64;

        // ---- S = (q*scale) . k^T ; C/D: row=quad*4+reg, col(s)=sub*16+col
        f32x4 sc[4];
        #pragma unroll
        for (int sub = 0; sub < 4; ++sub) {
            const ushort* kr = kb + (size_t)(s0 + sub * 16 + col) * HD;
            const bf16x8 k0 = *(const bf16x8*)(kr + quad * 8);
            const bf16x8 k1 = *(const bf16x8*)(kr + 32 + quad * 8);
            f32x4 z = {0.f, 0.f, 0.f, 0.f};
            z = __builtin_amdgcn_mfma_f32_16x16x32_bf16(aq0, k0, z, 0, 0, 0);
            z = __builtin_amdgcn_mfma_f32_16x16x32_bf16(aq1, k1, z, 0, 0, 0);
            sc[sub] = z;
        }

        if (it == nt - 1) {                           // only the diagonal tile masks
            #pragma unroll
            for (int sub = 0; sub < 4; ++sub)
                #pragma unroll
                for (int i = 0; i < 4; ++i) {
                    const int s = s0 + sub * 16 + col, t = t0 + quad * 4 + i;
                    if (s > t) sc[sub][i] = -1e30f;
                }
        }

        // ---- online softmax (rows in (quad,reg); butterfly over 16 lanes/quad)
        float mx[4], alpha[4], ps[4];
        #pragma unroll
        for (int i = 0; i < 4; ++i)
            mx[i] = fmaxf(fmaxf(sc[0][i], sc[1][i]), fmaxf(sc[2][i], sc[3][i]));
        #pragma unroll
        for (int d = 1; d < 16; d <<= 1)
            #pragma unroll
            for (int i = 0; i < 4; ++i) mx[i] = fmaxf(mx[i], __shfl_xor(mx[i], d, 64));
        #pragma unroll
        for (int i = 0; i < 4; ++i) {
            const float nm = fmaxf(m_r[i], mx[i]);
            alpha[i] = exp2f(m_r[i] - nm);
            m_r[i] = nm;
            ps[i] = 0.f;
        }
        #pragma unroll
        for (int sub = 0; sub < 4; ++sub)
            #pragma unroll
            for (int i = 0; i < 4; ++i) {
                const float p = exp2f(sc[sub][i] - m_r[i]);
                ps[i] += p;
                pt[quad * 4 + i][sub * 16 + col] = f2bf(p);
            }
        #pragma unroll
        for (int d = 1; d < 16; d <<= 1)
            #pragma unroll
            for (int i = 0; i < 4; ++i) ps[i] += __shfl_xor(ps[i], d, 64);
        #pragma unroll
        for (int i = 0; i < 4; ++i) l_r[i] = l_r[i] * alpha[i] + ps[i];
        #pragma unroll
        for (int sub = 0; sub < 4; ++sub)
            #pragma unroll
            for (int i = 0; i < 4; ++i) o[sub][i] *= alpha[i];

        // ---- P: C/D -> A-operand via LDS (same-wave: waitcnt only, no barrier)
        __asm__ volatile("s_waitcnt lgkmcnt(0)" ::: "memory");
        const bf16x8 ap0 = *(const bf16x8*)&pt[col][quad * 8];
        const bf16x8 ap1 = *(const bf16x8*)&pt[col][32 + quad * 8];

        // ---- O += P @ V  (B-frag rows = v^T[h][s], contiguous over s)
        #pragma unroll
        for (int sub = 0; sub < 4; ++sub) {
            const ushort* vr = vb + (size_t)(sub * 16 + col) * SEQ + s0;
            const bf16x8 v0 = *(const bf16x8*)(vr + quad * 8);
            const bf16x8 v1 = *(const bf16x8*)(vr + 32 + quad * 8);
            o[sub] = __builtin_amdgcn_mfma_f32_16x16x32_bf16(ap0, v0, o[sub], 0, 0, 0);
            o[sub] = __builtin_amdgcn_mfma_f32_16x16x32_bf16(ap1, v1, o[sub], 0, 0, 0);
        }
    }

    // ---- publish unnormalized partial (m, l, O)
    const size_t base = ((size_t)(b * 128 + tile)) * 8 + j;
    float* Op = pO + base * 1024;
    #pragma unroll
    for (int sub = 0; sub < 4; ++sub)
        #pragma unroll
        for (int i = 0; i < 4; ++i)
            Op[(quad * 4 + i) * 64 + sub * 16 + col] = o[sub][i];
    if (col == 0) {
        #pragma unroll
        for (int i = 0; i < 4; ++i) {
            pm[base * 16 + quad * 4 + i] = m_r[i];
            pl[base * 16 + quad * 4 + i] = l_r[i];
        }
    }
}

// ---------------- attention pass 2: merge 8 key-split partials --------------
__global__ __launch_bounds__(256) void attn_merge(
    const float* __restrict__ pm, const float* __restrict__ pl,
    const float* __restrict__ pO, float* __restrict__ out)
{
    const int blk = (int)blockIdx.x;                  // b*128 + tile
    const int b = blk >> 7, t0 = (blk & 127) * 16;
    const int tid = (int)threadIdx.x;
    const int row = tid >> 4, c0 = (tid & 15) * 4;
    const size_t base = (size_t)blk * 8;

    float mj[8];
    float ms = -1e30f;
    #pragma unroll
    for (int j = 0; j < 8; ++j) {
        mj[j] = pm[(base + j) * 16 + row];
        ms = fmaxf(ms, mj[j]);
    }
    float ls = 0.f;
    float4 r = {0.f, 0.f, 0.f, 0.f};
    #pragma unroll
    for (int j = 0; j < 8; ++j) {
        const float w = exp2f(mj[j] - ms);            // empty split: w -> 0
        ls += w * pl[(base + j) * 16 + row];
        const float4 O = *(const float4*)&pO[(base + j) * 1024 + row * 64 + c0];
        r.x += w * O.x; r.y += w * O.y; r.z += w * O.z; r.w += w * O.w;
    }
    const float rinv = 1.0f / ls;
    float4 res = {r.x * rinv, r.y * rinv, r.z * rinv, r.w * rinv};
    *(float4*)(out + ((size_t)b * SEQ + t0 + row) * HD + c0) = res;
}

extern "C" void kernel_launch(void* const* d_in, const int* in_sizes, int n_in,
                              void* d_out, int out_size, void* d_ws, size_t ws_size,
                              hipStream_t stream)
{
    const float* x  = (const float*)d_in[0];
    const float* Wq = (const float*)d_in[1];
    const float* bq = (const float*)d_in[2];
    const float* Wk = (const float*)d_in[3];
    const float* bk = (const float*)d_in[4];
    const float* Wv = (const float*)d_in[5];
    const float* bv = (const float*)d_in[6];
    float* out = (float*)d_out;

    char* ws = (char*)d_ws;
    ushort* Wb    = (ushort*)(ws);                      // 384 KB
    float*  bb    = (float*)(ws + 0x60000);             // 768 B
    ushort* qb    = (ushort*)(ws + 0x61000);            // 1 MB
    ushort* kbuf  = (ushort*)(ws + 0x161000);           // 1 MB
    ushort* vtb   = (ushort*)(ws + 0x261000);           // 1 MB
    float*  qpart = (float*)(ws + 0x400000);            // 512*8*12*256*4 = 48 MB
    float*  pmb   = (float*)(ws + 0x3400000);           // 256 KB
    float*  plb   = (float*)(ws + 0x3440000);           // 256 KB
    float*  pOb   = (float*)(ws + 0x3480000);           // 4*128*8*1024*4 = 16 MB

    prep<<<192, 256, 0, stream>>>(Wq, bq, Wk, bk, Wv, bv, Wb, bb);
    qkv_part<<<512 * 8, 64, 0, stream>>>(x, Wb, qpart);
    qkv_pack<<<512, 256, 0, stream>>>(qpart, bb, qb, kbuf, vtb);
    attn_part<<<4096, 64, 0, stream>>>(qb, kbuf, vtb, pmb, plb, pOb);
    attn_merge<<<512, 256, 0, stream>>>(pmb, plb, pOb, out);
}